// Round 5
// baseline (246.805 us; speedup 1.0000x reference)
//
#include <hip/hip_runtime.h>

#define D 96
#define D4 24
#define R 8   // atomic-shard replicas (power of 2)

static inline size_t alignup(size_t x) { return (x + 255) & ~size_t(255); }

__device__ inline float4 f4fma(float s, float4 a, float4 acc) {
    acc.x = fmaf(s, a.x, acc.x);
    acc.y = fmaf(s, a.y, acc.y);
    acc.z = fmaf(s, a.z, acc.z);
    acc.w = fmaf(s, a.w, acc.w);
    return acc;
}

__global__ void zero_kernel(int4* __restrict__ p, int n4) {
    int i = blockIdx.x * blockDim.x + threadIdx.x;
    if (i < n4) p[i] = make_int4(0, 0, 0, 0);
}

// Sharded degree count: cnt[r][i], r = blockIdx & 7.
__global__ void count_deg_kernel(const int* __restrict__ dst, int E,
                                 int* __restrict__ cnt, int n) {
    int e = blockIdx.x * blockDim.x + threadIdx.x;
    if (e < E) atomicAdd(&cnt[(blockIdx.x & (R - 1)) * n + dst[e]], 1);
}

// Phase 1: per-block exclusive scan of deg (=sum over replicas) -> rowptr (local),
// block totals -> bsum. Fused: dinv[i] = rsqrt(deg+1).
__global__ __launch_bounds__(1024) void scan_blocks_kernel(const int* __restrict__ cnt,
                                                           int* __restrict__ rowptr,
                                                           float* __restrict__ dinv,
                                                           int* __restrict__ bsum, int n) {
    __shared__ int wsum[16];
    const int i = blockIdx.x * 1024 + threadIdx.x;
    const int lane = threadIdx.x & 63;
    const int wid  = threadIdx.x >> 6;
    int v = 0;
    if (i < n) {
        #pragma unroll
        for (int r = 0; r < R; ++r) v += cnt[r * n + i];
        dinv[i] = rsqrtf((float)(v + 1));  // +1 = self-loop
    }
    int sc = v;
    #pragma unroll
    for (int off = 1; off < 64; off <<= 1) {
        int t = __shfl_up(sc, off);
        if (lane >= off) sc += t;
    }
    if (lane == 63) wsum[wid] = sc;
    __syncthreads();
    int wprefix = 0;
    #pragma unroll
    for (int k = 0; k < 16; ++k)
        if (k < wid) wprefix += wsum[k];
    if (i < n) rowptr[i] = wprefix + (sc - v);
    if (threadIdx.x == 1023) bsum[blockIdx.x] = wprefix + sc;
}

// Phase 2: one block scans block sums (nb <= 1024).
__global__ __launch_bounds__(1024) void scan_partials_kernel(const int* __restrict__ bsum,
                                                             int* __restrict__ boff,
                                                             int* __restrict__ rowptr,
                                                             int nb, int n) {
    __shared__ int wsum[16];
    const int lane = threadIdx.x & 63;
    const int wid  = threadIdx.x >> 6;
    int v = ((int)threadIdx.x < nb) ? bsum[threadIdx.x] : 0;
    int sc = v;
    #pragma unroll
    for (int off = 1; off < 64; off <<= 1) {
        int t = __shfl_up(sc, off);
        if (lane >= off) sc += t;
    }
    if (lane == 63) wsum[wid] = sc;
    __syncthreads();
    int wprefix = 0;
    #pragma unroll
    for (int k = 0; k < 16; ++k)
        if (k < wid) wprefix += wsum[k];
    if ((int)threadIdx.x < nb) boff[threadIdx.x] = wprefix + (sc - v);
    if ((int)threadIdx.x == nb - 1) rowptr[n] = wprefix + sc;
}

// Phase 3: globalize rowptr; emit per-replica running cursors rowrep[r][i].
__global__ __launch_bounds__(1024) void scan_add_replica_kernel(int* __restrict__ rowptr,
                                                                const int* __restrict__ boff,
                                                                const int* __restrict__ cnt,
                                                                int* __restrict__ rowrep, int n) {
    int i = blockIdx.x * 1024 + threadIdx.x;
    if (i < n) {
        int base = rowptr[i] + boff[blockIdx.x];
        rowptr[i] = base;
        int run = base;
        #pragma unroll
        for (int r = 0; r < R; ++r) {
            rowrep[r * n + i] = run;
            run += cnt[r * n + i];
        }
    }
}

// Sharded placement: 4 B scatter (src only).
__global__ void fill_csr_kernel(const int* __restrict__ src, const int* __restrict__ dst, int E,
                                int* __restrict__ rowrep, int n, int* __restrict__ csr_src) {
    int e = blockIdx.x * blockDim.x + threadIdx.x;
    if (e < E) {
        int d = dst[e], s = src[e];
        int pos = atomicAdd(&rowrep[(blockIdx.x & (R - 1)) * n + d], 1);
        csr_src[pos] = s;
    }
}

// Y[n,96] = X[n,96] @ W[96,96].
// block (24,8)=192 threads, 64 rows/block; thread computes 8 rows x 4 cols.
__global__ __launch_bounds__(192) void matmul_kernel(const float* __restrict__ X,
                                                     const float* __restrict__ W,
                                                     float* __restrict__ Y, int n) {
    __shared__ float XsT[96 * 64];
    const int t = threadIdx.x;        // 0..23 col-group (float4)
    const int y = threadIdx.y;        // 0..7 row-group
    const int tid = y * 24 + t;
    const int row0 = blockIdx.x * 64;
    const float4* X4 = (const float4*)X;

    for (int i = tid; i < 64 * 24; i += 192) {
        int r = i / 24, c4 = i % 24;
        float4 v = make_float4(0.f, 0.f, 0.f, 0.f);
        if (row0 + r < n) v = X4[(size_t)(row0 + r) * D4 + c4];
        int rs = r ^ ((c4 & 15) << 2);
        XsT[(c4 * 4 + 0) * 64 + rs] = v.x;
        XsT[(c4 * 4 + 1) * 64 + rs] = v.y;
        XsT[(c4 * 4 + 2) * 64 + rs] = v.z;
        XsT[(c4 * 4 + 3) * 64 + rs] = v.w;
    }
    __syncthreads();

    const float4* W4 = (const float4*)W;
    float4 acc[8];
    #pragma unroll
    for (int r = 0; r < 8; ++r) acc[r] = make_float4(0.f, 0.f, 0.f, 0.f);
    const int rbase = y * 8;

    #pragma unroll 8
    for (int k = 0; k < 96; ++k) {
        float4 w = W4[k * D4 + t];
        int base0 = (rbase ^ (((k >> 2) & 15) << 2));
        float4 xa = *(const float4*)&XsT[k * 64 + base0];
        float4 xb = *(const float4*)&XsT[k * 64 + (base0 ^ 4)];
        acc[0] = f4fma(xa.x, w, acc[0]);
        acc[1] = f4fma(xa.y, w, acc[1]);
        acc[2] = f4fma(xa.z, w, acc[2]);
        acc[3] = f4fma(xa.w, w, acc[3]);
        acc[4] = f4fma(xb.x, w, acc[4]);
        acc[5] = f4fma(xb.y, w, acc[5]);
        acc[6] = f4fma(xb.z, w, acc[6]);
        acc[7] = f4fma(xb.w, w, acc[7]);
    }

    #pragma unroll
    for (int r = 0; r < 8; ++r) {
        int row = row0 + rbase + r;
        if (row < n) ((float4*)Y)[(size_t)row * D4 + t] = acc[r];
    }
}

// out[i,:] = prelu( dinv[i]*sum_e dinv[src]*XW[src,:] + dinv[i]^2*XW[i,:] + b )
// block (24,16): 24 threads/node, 16 nodes/block; edge loop unrolled x8 for MLP.
__global__ __launch_bounds__(384) void aggregate_kernel(const float4* __restrict__ XW4,
                                                        const int* __restrict__ csr_src,
                                                        const int* __restrict__ rowptr,
                                                        const float* __restrict__ dinv,
                                                        const float4* __restrict__ b4,
                                                        const float4* __restrict__ pa4,
                                                        float4* __restrict__ out4, int n) {
    const int i = blockIdx.x * 16 + threadIdx.y;
    const int t = threadIdx.x;  // 0..23
    if (i >= n) return;
    const int beg = rowptr[i], end = rowptr[i + 1];
    const float di = dinv[i];
    float4 self = XW4[(size_t)i * D4 + t];
    float4 b = b4[t], a = pa4[t];
    float4 acc = make_float4(0.f, 0.f, 0.f, 0.f);
    int p = beg;
    for (; p + 8 <= end; p += 8) {
        int s0 = csr_src[p + 0];
        int s1 = csr_src[p + 1];
        int s2 = csr_src[p + 2];
        int s3 = csr_src[p + 3];
        int s4 = csr_src[p + 4];
        int s5 = csr_src[p + 5];
        int s6 = csr_src[p + 6];
        int s7 = csr_src[p + 7];
        float w0 = dinv[s0], w1 = dinv[s1], w2 = dinv[s2], w3 = dinv[s3];
        float w4 = dinv[s4], w5 = dinv[s5], w6 = dinv[s6], w7 = dinv[s7];
        float4 r0 = XW4[(size_t)s0 * D4 + t];
        float4 r1 = XW4[(size_t)s1 * D4 + t];
        float4 r2 = XW4[(size_t)s2 * D4 + t];
        float4 r3 = XW4[(size_t)s3 * D4 + t];
        float4 r4 = XW4[(size_t)s4 * D4 + t];
        float4 r5 = XW4[(size_t)s5 * D4 + t];
        float4 r6 = XW4[(size_t)s6 * D4 + t];
        float4 r7 = XW4[(size_t)s7 * D4 + t];
        acc = f4fma(w0, r0, acc);
        acc = f4fma(w1, r1, acc);
        acc = f4fma(w2, r2, acc);
        acc = f4fma(w3, r3, acc);
        acc = f4fma(w4, r4, acc);
        acc = f4fma(w5, r5, acc);
        acc = f4fma(w6, r6, acc);
        acc = f4fma(w7, r7, acc);
    }
    if (p + 4 <= end) {
        int s0 = csr_src[p + 0];
        int s1 = csr_src[p + 1];
        int s2 = csr_src[p + 2];
        int s3 = csr_src[p + 3];
        float w0 = dinv[s0], w1 = dinv[s1], w2 = dinv[s2], w3 = dinv[s3];
        float4 r0 = XW4[(size_t)s0 * D4 + t];
        float4 r1 = XW4[(size_t)s1 * D4 + t];
        float4 r2 = XW4[(size_t)s2 * D4 + t];
        float4 r3 = XW4[(size_t)s3 * D4 + t];
        acc = f4fma(w0, r0, acc);
        acc = f4fma(w1, r1, acc);
        acc = f4fma(w2, r2, acc);
        acc = f4fma(w3, r3, acc);
        p += 4;
    }
    for (; p < end; ++p) {
        int s = csr_src[p];
        acc = f4fma(dinv[s], XW4[(size_t)s * D4 + t], acc);
    }
    float4 v;
    v.x = fmaf(di, acc.x, di * di * self.x) + b.x;
    v.y = fmaf(di, acc.y, di * di * self.y) + b.y;
    v.z = fmaf(di, acc.z, di * di * self.z) + b.z;
    v.w = fmaf(di, acc.w, di * di * self.w) + b.w;
    v.x = v.x > 0.f ? v.x : a.x * v.x;
    v.y = v.y > 0.f ? v.y : a.y * v.y;
    v.z = v.z > 0.f ? v.z : a.z * v.z;
    v.w = v.w > 0.f ? v.w : a.w * v.w;
    out4[(size_t)i * D4 + t] = v;
}

extern "C" void kernel_launch(void* const* d_in, const int* in_sizes, int n_in,
                              void* d_out, int out_size, void* d_ws, size_t ws_size,
                              hipStream_t stream) {
    const float* x   = (const float*)d_in[0];
    const int*   ei  = (const int*)d_in[1];
    const float* W1  = (const float*)d_in[2];
    const float* b1  = (const float*)d_in[3];
    const float* W2  = (const float*)d_in[4];
    const float* b2  = (const float*)d_in[5];
    const float* pa  = (const float*)d_in[6];
    const int n = in_sizes[0] / D;
    const int E = in_sizes[1] / 2;
    const int* srcp = ei;
    const int* dstp = ei + E;

    char* w = (char*)d_ws;
    int*   cnt     = (int*)w;   w += alignup((size_t)R * n * 4);
    int*   rowrep  = (int*)w;   w += alignup((size_t)R * n * 4);
    float* dinv    = (float*)w; w += alignup((size_t)n * 4);
    int*   rowptr  = (int*)w;   w += alignup((size_t)(n + 1) * 4);
    int*   bsum    = (int*)w;   w += alignup(1024 * 4);
    int*   boff    = (int*)w;   w += alignup(1024 * 4);
    int*   csr_src = (int*)w;   w += alignup((size_t)E * 4);
    float* xw      = (float*)w; w += alignup((size_t)n * D * 4);
    float* out     = (float*)d_out;

    const int tb = 256;
    const int nb = (n + 1023) / 1024;
    const int cnt4 = (R * n) / 4;
    zero_kernel<<<(cnt4 + tb - 1) / tb, tb, 0, stream>>>((int4*)cnt, cnt4);
    count_deg_kernel<<<(E + tb - 1) / tb, tb, 0, stream>>>(dstp, E, cnt, n);
    scan_blocks_kernel<<<nb, 1024, 0, stream>>>(cnt, rowptr, dinv, bsum, n);
    scan_partials_kernel<<<1, 1024, 0, stream>>>(bsum, boff, rowptr, nb, n);
    scan_add_replica_kernel<<<nb, 1024, 0, stream>>>(rowptr, boff, cnt, rowrep, n);
    fill_csr_kernel<<<(E + tb - 1) / tb, tb, 0, stream>>>(srcp, dstp, E, rowrep, n, csr_src);

    dim3 mblk(24, 8);
    const int mgrid = (n + 63) / 64;
    dim3 ablk(24, 16);
    const int agrid = (n + 15) / 16;

    matmul_kernel<<<mgrid, mblk, 0, stream>>>(x, W1, xw, n);
    aggregate_kernel<<<agrid, ablk, 0, stream>>>((const float4*)xw, csr_src, rowptr, dinv,
                                                 (const float4*)b1, (const float4*)pa, (float4*)out, n);
    matmul_kernel<<<mgrid, mblk, 0, stream>>>(out, W2, xw, n);
    aggregate_kernel<<<agrid, ablk, 0, stream>>>((const float4*)xw, csr_src, rowptr, dinv,
                                                 (const float4*)b2, (const float4*)pa, (float4*)out, n);
}

// Round 6
// 206.672 us; speedup vs baseline: 1.1942x; 1.1942x over previous
//
#include <hip/hip_runtime.h>
#include <hip/hip_fp16.h>

#define D 96
#define D4 24

static inline size_t alignup(size_t x) { return (x + 255) & ~size_t(255); }

__device__ inline float4 f4fma(float s, float4 a, float4 acc) {
    acc.x = fmaf(s, a.x, acc.x);
    acc.y = fmaf(s, a.y, acc.y);
    acc.z = fmaf(s, a.z, acc.z);
    acc.w = fmaf(s, a.w, acc.w);
    return acc;
}

// gather one fp16 row chunk (8B = 4 halves) and FMA into acc
__device__ inline float4 h4fma(const uint2* __restrict__ XH, int s, int t, float w, float4 acc) {
    uint2 rv = XH[(size_t)s * D4 + t];
    __half2 ha = *reinterpret_cast<__half2*>(&rv.x);
    __half2 hb = *reinterpret_cast<__half2*>(&rv.y);
    float2 f0 = __half22float2(ha);
    float2 f1 = __half22float2(hb);
    acc.x = fmaf(w, f0.x, acc.x);
    acc.y = fmaf(w, f0.y, acc.y);
    acc.z = fmaf(w, f1.x, acc.z);
    acc.w = fmaf(w, f1.y, acc.w);
    return acc;
}

__global__ void zero_kernel(int4* __restrict__ p, int n4) {
    int i = blockIdx.x * blockDim.x + threadIdx.x;
    if (i < n4) p[i] = make_int4(0, 0, 0, 0);
}

// 4 edges per thread, explicitly unrolled: 4 independent fire-and-forget atomics.
__global__ void count_deg_kernel(const int* __restrict__ dst, int E,
                                 int* __restrict__ deg, int S) {
    int t = blockIdx.x * blockDim.x + threadIdx.x;
    int e0 = t, e1 = t + S, e2 = t + 2 * S, e3 = t + 3 * S;
    int d0 = (e0 < E) ? dst[e0] : -1;
    int d1 = (e1 < E) ? dst[e1] : -1;
    int d2 = (e2 < E) ? dst[e2] : -1;
    int d3 = (e3 < E) ? dst[e3] : -1;
    if (d0 >= 0) atomicAdd(&deg[d0], 1);
    if (d1 >= 0) atomicAdd(&deg[d1], 1);
    if (d2 >= 0) atomicAdd(&deg[d2], 1);
    if (d3 >= 0) atomicAdd(&deg[d3], 1);
}

// Phase 1: per-block exclusive scan of deg -> rowptr (local), block totals -> bsum.
// Fused: dinv[i] = rsqrt(deg[i]+1).
__global__ __launch_bounds__(1024) void scan_blocks_kernel(const int* __restrict__ deg,
                                                           int* __restrict__ rowptr,
                                                           float* __restrict__ dinv,
                                                           int* __restrict__ bsum, int n) {
    __shared__ int wsum[16];
    const int i = blockIdx.x * 1024 + threadIdx.x;
    const int lane = threadIdx.x & 63;
    const int wid  = threadIdx.x >> 6;
    int v = (i < n) ? deg[i] : 0;
    if (i < n) dinv[i] = rsqrtf((float)(v + 1));  // +1 = self-loop
    int sc = v;
    #pragma unroll
    for (int off = 1; off < 64; off <<= 1) {
        int t = __shfl_up(sc, off);
        if (lane >= off) sc += t;
    }
    if (lane == 63) wsum[wid] = sc;
    __syncthreads();
    int wprefix = 0;
    #pragma unroll
    for (int k = 0; k < 16; ++k)
        if (k < wid) wprefix += wsum[k];
    if (i < n) rowptr[i] = wprefix + (sc - v);
    if (threadIdx.x == 1023) bsum[blockIdx.x] = wprefix + sc;
}

// Phase 2: one block scans block sums (nb <= 1024).
__global__ __launch_bounds__(1024) void scan_partials_kernel(const int* __restrict__ bsum,
                                                             int* __restrict__ boff,
                                                             int* __restrict__ rowptr,
                                                             int nb, int n) {
    __shared__ int wsum[16];
    const int lane = threadIdx.x & 63;
    const int wid  = threadIdx.x >> 6;
    int v = ((int)threadIdx.x < nb) ? bsum[threadIdx.x] : 0;
    int sc = v;
    #pragma unroll
    for (int off = 1; off < 64; off <<= 1) {
        int t = __shfl_up(sc, off);
        if (lane >= off) sc += t;
    }
    if (lane == 63) wsum[wid] = sc;
    __syncthreads();
    int wprefix = 0;
    #pragma unroll
    for (int k = 0; k < 16; ++k)
        if (k < wid) wprefix += wsum[k];
    if ((int)threadIdx.x < nb) boff[threadIdx.x] = wprefix + (sc - v);
    if ((int)threadIdx.x == nb - 1) rowptr[n] = wprefix + sc;
}

// Phase 3: globalize rowptr; emit rowbase copy that fill_csr bumps in place.
__global__ __launch_bounds__(1024) void scan_add_kernel(int* __restrict__ rowptr,
                                                        int* __restrict__ rowbase,
                                                        const int* __restrict__ boff, int n) {
    int i = blockIdx.x * 1024 + threadIdx.x;
    if (i < n) {
        int v = rowptr[i] + boff[blockIdx.x];
        rowptr[i] = v;
        rowbase[i] = v;
    }
}

// 4 edges per thread, explicitly unrolled: 4 independent atomic-with-return chains.
__global__ void fill_csr_kernel(const int* __restrict__ src, const int* __restrict__ dst, int E,
                                int* __restrict__ rowbase,
                                const float* __restrict__ dinv, int2* __restrict__ csr, int S) {
    int t = blockIdx.x * blockDim.x + threadIdx.x;
    int e0 = t, e1 = t + S, e2 = t + 2 * S, e3 = t + 3 * S;
    bool v0 = e0 < E, v1 = e1 < E, v2 = e2 < E, v3 = e3 < E;
    int d0 = 0, d1 = 0, d2 = 0, d3 = 0, s0 = 0, s1 = 0, s2 = 0, s3 = 0;
    if (v0) { d0 = dst[e0]; s0 = src[e0]; }
    if (v1) { d1 = dst[e1]; s1 = src[e1]; }
    if (v2) { d2 = dst[e2]; s2 = src[e2]; }
    if (v3) { d3 = dst[e3]; s3 = src[e3]; }
    float w0 = v0 ? dinv[s0] : 0.f;
    float w1 = v1 ? dinv[s1] : 0.f;
    float w2 = v2 ? dinv[s2] : 0.f;
    float w3 = v3 ? dinv[s3] : 0.f;
    int p0 = 0, p1 = 0, p2 = 0, p3 = 0;
    if (v0) p0 = atomicAdd(&rowbase[d0], 1);
    if (v1) p1 = atomicAdd(&rowbase[d1], 1);
    if (v2) p2 = atomicAdd(&rowbase[d2], 1);
    if (v3) p3 = atomicAdd(&rowbase[d3], 1);
    if (v0) csr[p0] = make_int2(s0, __float_as_int(w0));
    if (v1) csr[p1] = make_int2(s1, __float_as_int(w1));
    if (v2) csr[p2] = make_int2(s2, __float_as_int(w2));
    if (v3) csr[p3] = make_int2(s3, __float_as_int(w3));
}

// Y[n,96](fp16) = X[n,96](fp32) @ W[96,96](fp32).
// block (24,8)=192 threads, 64 rows/block; thread computes 8 rows x 4 cols.
__global__ __launch_bounds__(192) void matmul_kernel(const float* __restrict__ X,
                                                     const float* __restrict__ W,
                                                     uint2* __restrict__ Y, int n) {
    __shared__ float XsT[96 * 64];
    const int t = threadIdx.x;        // 0..23 col-group
    const int y = threadIdx.y;        // 0..7 row-group
    const int tid = y * 24 + t;
    const int row0 = blockIdx.x * 64;
    const float4* X4 = (const float4*)X;

    for (int i = tid; i < 64 * 24; i += 192) {
        int r = i / 24, c4 = i % 24;
        float4 v = make_float4(0.f, 0.f, 0.f, 0.f);
        if (row0 + r < n) v = X4[(size_t)(row0 + r) * D4 + c4];
        int rs = r ^ ((c4 & 15) << 2);
        XsT[(c4 * 4 + 0) * 64 + rs] = v.x;
        XsT[(c4 * 4 + 1) * 64 + rs] = v.y;
        XsT[(c4 * 4 + 2) * 64 + rs] = v.z;
        XsT[(c4 * 4 + 3) * 64 + rs] = v.w;
    }
    __syncthreads();

    const float4* W4 = (const float4*)W;
    float4 acc[8];
    #pragma unroll
    for (int r = 0; r < 8; ++r) acc[r] = make_float4(0.f, 0.f, 0.f, 0.f);
    const int rbase = y * 8;

    #pragma unroll 8
    for (int k = 0; k < 96; ++k) {
        float4 w = W4[k * D4 + t];
        int base0 = (rbase ^ (((k >> 2) & 15) << 2));
        float4 xa = *(const float4*)&XsT[k * 64 + base0];
        float4 xb = *(const float4*)&XsT[k * 64 + (base0 ^ 4)];
        acc[0] = f4fma(xa.x, w, acc[0]);
        acc[1] = f4fma(xa.y, w, acc[1]);
        acc[2] = f4fma(xa.z, w, acc[2]);
        acc[3] = f4fma(xa.w, w, acc[3]);
        acc[4] = f4fma(xb.x, w, acc[4]);
        acc[5] = f4fma(xb.y, w, acc[5]);
        acc[6] = f4fma(xb.z, w, acc[6]);
        acc[7] = f4fma(xb.w, w, acc[7]);
    }

    #pragma unroll
    for (int r = 0; r < 8; ++r) {
        int row = row0 + rbase + r;
        if (row < n) {
            __half2 ha = __float22half2_rn(make_float2(acc[r].x, acc[r].y));
            __half2 hb = __float22half2_rn(make_float2(acc[r].z, acc[r].w));
            uint2 st;
            st.x = *reinterpret_cast<unsigned int*>(&ha);
            st.y = *reinterpret_cast<unsigned int*>(&hb);
            Y[(size_t)row * D4 + t] = st;
        }
    }
}

// out[i,:] = prelu( dinv[i]*sum_e w_e*XW[src_e,:] + dinv[i]^2*XW[i,:] + b ), XW in fp16.
// block (24,16): 24 threads/node, 16 nodes/block; edge loop unrolled x8.
__global__ __launch_bounds__(384) void aggregate_kernel(const uint2* __restrict__ XH,
                                                        const int2* __restrict__ csr,
                                                        const int* __restrict__ rowptr,
                                                        const float* __restrict__ dinv,
                                                        const float4* __restrict__ b4,
                                                        const float4* __restrict__ pa4,
                                                        float4* __restrict__ out4, int n) {
    const int i = blockIdx.x * 16 + threadIdx.y;
    const int t = threadIdx.x;  // 0..23
    if (i >= n) return;
    const int beg = rowptr[i], end = rowptr[i + 1];
    float4 acc = make_float4(0.f, 0.f, 0.f, 0.f);
    int p = beg;
    for (; p + 8 <= end; p += 8) {
        int2 e0 = csr[p + 0];
        int2 e1 = csr[p + 1];
        int2 e2 = csr[p + 2];
        int2 e3 = csr[p + 3];
        int2 e4 = csr[p + 4];
        int2 e5 = csr[p + 5];
        int2 e6 = csr[p + 6];
        int2 e7 = csr[p + 7];
        acc = h4fma(XH, e0.x, t, __int_as_float(e0.y), acc);
        acc = h4fma(XH, e1.x, t, __int_as_float(e1.y), acc);
        acc = h4fma(XH, e2.x, t, __int_as_float(e2.y), acc);
        acc = h4fma(XH, e3.x, t, __int_as_float(e3.y), acc);
        acc = h4fma(XH, e4.x, t, __int_as_float(e4.y), acc);
        acc = h4fma(XH, e5.x, t, __int_as_float(e5.y), acc);
        acc = h4fma(XH, e6.x, t, __int_as_float(e6.y), acc);
        acc = h4fma(XH, e7.x, t, __int_as_float(e7.y), acc);
    }
    if (p + 4 <= end) {
        int2 e0 = csr[p + 0];
        int2 e1 = csr[p + 1];
        int2 e2 = csr[p + 2];
        int2 e3 = csr[p + 3];
        acc = h4fma(XH, e0.x, t, __int_as_float(e0.y), acc);
        acc = h4fma(XH, e1.x, t, __int_as_float(e1.y), acc);
        acc = h4fma(XH, e2.x, t, __int_as_float(e2.y), acc);
        acc = h4fma(XH, e3.x, t, __int_as_float(e3.y), acc);
        p += 4;
    }
    for (; p < end; ++p) {
        int2 e = csr[p];
        acc = h4fma(XH, e.x, t, __int_as_float(e.y), acc);
    }
    const float di = dinv[i];
    float4 self = make_float4(0.f, 0.f, 0.f, 0.f);
    self = h4fma(XH, i, t, 1.f, self);
    float4 b = b4[t], a = pa4[t];
    float4 v;
    v.x = fmaf(di, acc.x, di * di * self.x) + b.x;
    v.y = fmaf(di, acc.y, di * di * self.y) + b.y;
    v.z = fmaf(di, acc.z, di * di * self.z) + b.z;
    v.w = fmaf(di, acc.w, di * di * self.w) + b.w;
    v.x = v.x > 0.f ? v.x : a.x * v.x;
    v.y = v.y > 0.f ? v.y : a.y * v.y;
    v.z = v.z > 0.f ? v.z : a.z * v.z;
    v.w = v.w > 0.f ? v.w : a.w * v.w;
    out4[(size_t)i * D4 + t] = v;
}

extern "C" void kernel_launch(void* const* d_in, const int* in_sizes, int n_in,
                              void* d_out, int out_size, void* d_ws, size_t ws_size,
                              hipStream_t stream) {
    const float* x   = (const float*)d_in[0];
    const int*   ei  = (const int*)d_in[1];
    const float* W1  = (const float*)d_in[2];
    const float* b1  = (const float*)d_in[3];
    const float* W2  = (const float*)d_in[4];
    const float* b2  = (const float*)d_in[5];
    const float* pa  = (const float*)d_in[6];
    const int n = in_sizes[0] / D;
    const int E = in_sizes[1] / 2;
    const int* srcp = ei;
    const int* dstp = ei + E;

    char* w = (char*)d_ws;
    int*   deg     = (int*)w;   w += alignup((size_t)n * 4);
    int*   rowbase = (int*)w;   w += alignup((size_t)n * 4);
    float* dinv    = (float*)w; w += alignup((size_t)n * 4);
    int*   rowptr  = (int*)w;   w += alignup((size_t)(n + 1) * 4);
    int*   bsum    = (int*)w;   w += alignup(1024 * 4);
    int*   boff    = (int*)w;   w += alignup(1024 * 4);
    int2*  csr     = (int2*)w;  w += alignup((size_t)E * 8);
    uint2* xw      = (uint2*)w; w += alignup((size_t)n * D * 2);  // fp16 rows
    float* out     = (float*)d_out;

    const int tb = 256;
    const int nb = (n + 1023) / 1024;
    const int S = ((E + 3) / 4 + tb - 1) / tb * tb;  // threads (stride) for x4 edge kernels
    zero_kernel<<<(n / 4 + tb - 1) / tb, tb, 0, stream>>>((int4*)deg, n / 4);
    count_deg_kernel<<<S / tb, tb, 0, stream>>>(dstp, E, deg, S);
    scan_blocks_kernel<<<nb, 1024, 0, stream>>>(deg, rowptr, dinv, bsum, n);
    scan_partials_kernel<<<1, 1024, 0, stream>>>(bsum, boff, rowptr, nb, n);
    scan_add_kernel<<<nb, 1024, 0, stream>>>(rowptr, rowbase, boff, n);
    fill_csr_kernel<<<S / tb, tb, 0, stream>>>(srcp, dstp, E, rowbase, dinv, csr, S);

    dim3 mblk(24, 8);
    const int mgrid = (n + 63) / 64;
    dim3 ablk(24, 16);
    const int agrid = (n + 15) / 16;

    matmul_kernel<<<mgrid, mblk, 0, stream>>>(x, W1, xw, n);
    aggregate_kernel<<<agrid, ablk, 0, stream>>>(xw, csr, rowptr, dinv,
                                                 (const float4*)b1, (const float4*)pa, (float4*)out, n);
    matmul_kernel<<<mgrid, mblk, 0, stream>>>(out, W2, xw, n);
    aggregate_kernel<<<agrid, ablk, 0, stream>>>(xw, csr, rowptr, dinv,
                                                 (const float4*)b2, (const float4*)pa, (float4*)out, n);
}